// Round 3
// baseline (234.694 us; speedup 1.0000x reference)
//
#include <hip/hip_runtime.h>

// LayerNorm over last dim W=256 for (B=8, C=128, H=128, W=256) fp32,
// then per-channel affine: out = (x - mean)/sqrt(var+eps) * gain[c] + bias[c].
//
// v5: 8 rows per wave (two aligned 4-row groups), 16 lanes per row.
//  - Each lane issues 8 independent float4 loads (8 KB/wave in flight)
//    BEFORE any reduction: 2x the MLP of v4, 8x v2/v3. The kernel has
//    been latency-limited (~3.8-4.1 TB/s effective vs 6.8 TB/s fill BW,
//    with VALUBusy 12%, 0 conflicts, occupancy 65% in v3's counters).
//  - Two groups' butterflies = 4 independent 4-step shuffle chains (ILP).
//  - Nontemporal stores: output is never re-read by the kernel; normal
//    allocating stores evict the L3-resident input that currently absorbs
//    ~half the reads (v3: FETCH 65.5 MB vs 134 MB input). nt preserves it.
//  - Rows 8g..8g+7 share channel c = g>>4 (128 rows per channel), so
//    gain/bias are wave-uniform scalar loads.
// Memory-bound: 268 MB total traffic, roofline ~43 us at 6.3 TB/s.

#define W_DIM 256
#define C_DIM 128
#define EPS 1e-8f

typedef float f32x4 __attribute__((ext_vector_type(4)));

__device__ __forceinline__ void accum(const f32x4 v, float& s, float& q)
{
    s += (v.x + v.y) + (v.z + v.w);
    q = fmaf(v.x, v.x, q); q = fmaf(v.y, v.y, q);
    q = fmaf(v.z, v.z, q); q = fmaf(v.w, v.w, q);
}

__device__ __forceinline__ f32x4 affine(const f32x4 v, const float a, const float bb)
{
    f32x4 o;
    o.x = fmaf(v.x, a, bb); o.y = fmaf(v.y, a, bb);
    o.z = fmaf(v.z, a, bb); o.w = fmaf(v.w, a, bb);
    return o;
}

__global__ __launch_bounds__(256) void tLNv5_kernel(
    const float* __restrict__ inp,
    const float* __restrict__ gain,
    const float* __restrict__ bias,
    float* __restrict__ out,
    const int rows)
{
    const int lane = threadIdx.x & 63;
    const int sub  = lane & 15;          // lane within its row (16 lanes/row)
    const int quad = lane >> 4;          // which row of each 4-row group
    const int gw   = (int)(blockIdx.x << 2) + (threadIdx.x >> 6);  // wave id

    const int r0 = (gw << 3) + quad;     // first group's row; second = r0+4
    if (r0 >= rows) return;

    const f32x4* __restrict__ in4  = (const f32x4*)inp;
    f32x4* __restrict__       out4 = (f32x4*)out;

    const size_t b0 = (size_t)r0 * 64 + sub;
    const size_t b1 = b0 + 256;          // (r0+4) * 64 elements later

    // ---- 8 independent loads, all in flight before any use ----
    f32x4 a0 = in4[b0];
    f32x4 a1 = in4[b0 + 16];
    f32x4 a2 = in4[b0 + 32];
    f32x4 a3 = in4[b0 + 48];
    f32x4 c0 = in4[b1];
    f32x4 c1 = in4[b1 + 16];
    f32x4 c2 = in4[b1 + 32];
    f32x4 c3 = in4[b1 + 48];

    // ---- per-lane partials for both groups ----
    float sA = 0.f, qA = 0.f, sB = 0.f, qB = 0.f;
    accum(a0, sA, qA); accum(a1, sA, qA); accum(a2, sA, qA); accum(a3, sA, qA);
    accum(c0, sB, qB); accum(c1, sB, qB); accum(c2, sB, qB); accum(c3, sB, qB);

    // ---- 4-step butterflies over the 16-lane row groups (4 indep chains) ----
    #pragma unroll
    for (int off = 1; off < 16; off <<= 1) {
        sA += __shfl_xor(sA, off, 64);
        qA += __shfl_xor(qA, off, 64);
        sB += __shfl_xor(sB, off, 64);
        qB += __shfl_xor(qB, off, 64);
    }

    // channel is uniform across the wave's 8 rows (128 rows per channel)
    const int   ch = (r0 >> 7) & (C_DIM - 1);
    const float g  = gain[ch];
    const float bv = bias[ch];

    const float meanA = sA * (1.0f / (float)W_DIM);
    const float varA  = qA * (1.0f / (float)W_DIM) - meanA * meanA;
    const float aA    = rsqrtf(varA + EPS) * g;
    const float bbA   = bv - meanA * aA;

    const float meanB = sB * (1.0f / (float)W_DIM);
    const float varB  = qB * (1.0f / (float)W_DIM) - meanB * meanB;
    const float aB    = rsqrtf(varB + EPS) * g;
    const float bbB   = bv - meanB * aB;

    // ---- nontemporal streaming stores (don't evict L3-resident input) ----
    __builtin_nontemporal_store(affine(a0, aA, bbA), &out4[b0]);
    __builtin_nontemporal_store(affine(a1, aA, bbA), &out4[b0 + 16]);
    __builtin_nontemporal_store(affine(a2, aA, bbA), &out4[b0 + 32]);
    __builtin_nontemporal_store(affine(a3, aA, bbA), &out4[b0 + 48]);
    __builtin_nontemporal_store(affine(c0, aB, bbB), &out4[b1]);
    __builtin_nontemporal_store(affine(c1, aB, bbB), &out4[b1 + 16]);
    __builtin_nontemporal_store(affine(c2, aB, bbB), &out4[b1 + 32]);
    __builtin_nontemporal_store(affine(c3, aB, bbB), &out4[b1 + 48]);
}

extern "C" void kernel_launch(void* const* d_in, const int* in_sizes, int n_in,
                              void* d_out, int out_size, void* d_ws, size_t ws_size,
                              hipStream_t stream)
{
    const float* inp  = (const float*)d_in[0];
    const float* gain = (const float*)d_in[1];
    const float* bias = (const float*)d_in[2];
    float* out = (float*)d_out;

    const int rows   = in_sizes[0] / W_DIM;     // 131072
    const int waves  = (rows + 7) / 8;          // 8 rows per wave
    const int blocks = (waves + 3) / 4;         // 4 waves per block -> 4096

    tLNv5_kernel<<<blocks, 256, 0, stream>>>(inp, gain, bias, out, rows);
}